// Round 7
// baseline (378.048 us; speedup 1.0000x reference)
//
#include <hip/hip_runtime.h>

#define NUM_USER 200000
#define NUM_EVENT 50000
#define NUM_EDGES 1000000
#define DDIM 64

// Bucketed CSR build: user buckets span 512 nodes, event buckets span 256.
#define NBU 391                // 391*512 = 200192 >= NUM_USER
#define NBE 196                // 196*256 = 50176 >= NUM_EVENT
#define NB (NBU + NBE)         // 587
#define CHUNK 2048
#define NCH ((NUM_EDGES + CHUNK - 1) / CHUNK)  // 489

// Fixed bucket capacities (counting-sort without count/scan passes).
// User bucket ~ Binomial(1M, 512/200000): mean 2560, sd ~50.5 -> 3072 = +10sd.
// Event bucket ~ Binomial(1M, 256/50000): mean 5120, sd ~71   -> 5632 = +7sd.
#define CAPU 3072
#define CAPE 5632

// MFMA linear: 16-row tiles per wave, prefetched, LDS-staged coalesced stores.
#define TU16 (NUM_USER / 16)   // 12500
#define TE16 (NUM_EVENT / 16)  // 3125
#define BL_GRID 2048           // 587 build blocks + 1461 linear blocks
#define LIN2_GRID 768          // exact residency at 3 blocks/CU

// Gather: persistent grid, phase-sequential
#define GGRID 2048

typedef __attribute__((ext_vector_type(8))) short short8v;  // 8 bf16 (4 VGPRs)
typedef __attribute__((ext_vector_type(4))) float f32x4;    // MFMA accumulator

// bf16 pair packing. Table word layout (MFMA-epilogue-native):
//   word w of a row (w=0..31) = (bf16(dim w+32) << 16) | bf16(dim w)
__device__ __forceinline__ unsigned int pack_bf2(float lo, float hi) {
  unsigned int ul = __float_as_uint(lo);
  unsigned int uh = __float_as_uint(hi);
  ul = (ul + 0x7FFFu + ((ul >> 16) & 1u)) >> 16;
  uh = (uh + 0x7FFFu + ((uh >> 16) & 1u)) & 0xFFFF0000u;
  return uh | ul;
}
__device__ __forceinline__ float bf_lo(unsigned int v) { return __uint_as_float(v << 16); }
__device__ __forceinline__ float bf_hi(unsigned int v) { return __uint_as_float(v & 0xFFFF0000u); }
__device__ __forceinline__ unsigned short bf_rne(float f) {
  unsigned int u = __float_as_uint(f);
  return (unsigned short)((u + 0x7FFFu + ((u >> 16) & 1u)) >> 16);
}
__device__ __forceinline__ float bf_val(unsigned short h) {
  return __uint_as_float(((unsigned int)h) << 16);
}

// ---------------- Scatter: single pass, fixed-capacity buckets ----------------
// itemU = (dst&511)<<16 | src ; itemE = (src&255)<<18 | dst
__global__ __launch_bounds__(256) void bucket_scatter_kernel(
    const int* __restrict__ src, const int* __restrict__ dst,
    int* __restrict__ cntU, int* __restrict__ cntE,
    unsigned int* __restrict__ itemsU, unsigned int* __restrict__ itemsE) {
  __shared__ int cnt[NB];
  __shared__ int cur[NB];
  for (int i = threadIdx.x; i < NB; i += 256) cnt[i] = 0;
  __syncthreads();
  const int e0 = blockIdx.x * CHUNK;
  const int e1 = min(e0 + CHUNK, NUM_EDGES);
  for (int i = e0 + threadIdx.x; i < e1; i += 256) {
    atomicAdd(&cnt[dst[i] >> 9], 1);
    atomicAdd(&cnt[NBU + (src[i] >> 8)], 1);
  }
  __syncthreads();
  for (int i = threadIdx.x; i < NB; i += 256) {
    int c = cnt[i];
    if (c) {
      if (i < NBU)
        cur[i] = i * CAPU + atomicAdd(&cntU[i], c);
      else
        cur[i] = (i - NBU) * CAPE + atomicAdd(&cntE[i - NBU], c);
    } else {
      cur[i] = 0;
    }
  }
  __syncthreads();
  for (int i = e0 + threadIdx.x; i < e1; i += 256) {
    const int s = src[i];
    const int d = dst[i];
    int r = atomicAdd(&cur[d >> 9], 1);
    itemsU[r] = ((unsigned int)(d & 511) << 16) | (unsigned int)s;
    int r2 = atomicAdd(&cur[NBU + (s >> 8)], 1);
    itemsE[r2] = ((unsigned int)(s & 255) << 18) | (unsigned int)d;
  }
}

// ---------------- Pass B bodies (share a union'd LDS buffer, 8192 B) ----------------

// user: one block per bucket of 512 users. smem: 512+256 ints = 3072 B.
__device__ __forceinline__ void build_user_body(
    unsigned char* smem, const int* __restrict__ cntU,
    const unsigned int* __restrict__ itemsU, int* __restrict__ offs,
    unsigned short* __restrict__ lists_u, int b) {
  int* cnt = (int*)smem;       // 512
  int* part = cnt + 512;       // 256
  const int istart = b * CAPU;
  const int iend = istart + cntU[b];
  const int tid = threadIdx.x;
  for (int i = tid; i < 512; i += 256) cnt[i] = 0;
  __syncthreads();
  for (int i = istart + tid; i < iend; i += 256)
    atomicAdd(&cnt[itemsU[i] >> 16], 1);
  __syncthreads();
  const int v0 = cnt[tid * 2];
  const int v1 = cnt[tid * 2 + 1];
  part[tid] = v0 + v1;
  __syncthreads();
  for (int off = 1; off < 256; off <<= 1) {
    int t = (tid >= off) ? part[tid - off] : 0;
    __syncthreads();
    part[tid] += t;
    __syncthreads();
  }
  int run = (tid == 0) ? 0 : part[tid - 1];
  const int node0 = b * 512;
  const int n = node0 + tid * 2;
  if (n < NUM_USER) offs[n] = istart + run + v0;  // END position (padded space)
  cnt[tid * 2] = run;                             // exclusive -> cursor
  run += v0;
  if (n + 1 < NUM_USER) offs[n + 1] = istart + run + v1;
  cnt[tid * 2 + 1] = run;
  __syncthreads();
  for (int i = istart + tid; i < iend; i += 256) {
    const unsigned int it = itemsU[i];
    int r = atomicAdd(&cnt[it >> 16], 1);
    lists_u[istart + r] = (unsigned short)(it & 0xFFFFu);
  }
}

// event: one block per bucket of 256 events. smem: 512 ints = 2048 B.
__device__ __forceinline__ void build_event_body(
    unsigned char* smem, const int* __restrict__ cntE,
    const unsigned int* __restrict__ itemsE, int* __restrict__ offs,
    int* __restrict__ lists_e, int b) {
  int* cnt = (int*)smem;   // 256
  int* s2 = cnt + 256;     // 256
  const int istart = b * CAPE;
  const int iend = istart + cntE[b];
  const int tid = threadIdx.x;
  cnt[tid] = 0;
  __syncthreads();
  for (int i = istart + tid; i < iend; i += 256)
    atomicAdd(&cnt[itemsE[i] >> 18], 1);
  __syncthreads();
  const int v = cnt[tid];
  s2[tid] = v;
  __syncthreads();
  for (int off = 1; off < 256; off <<= 1) {
    int t = (tid >= off) ? s2[tid - off] : 0;
    __syncthreads();
    s2[tid] += t;
    __syncthreads();
  }
  const int excl = s2[tid] - v;
  const int e0 = b * 256;
  if (e0 + tid < NUM_EVENT)
    offs[NUM_USER + e0 + tid] = istart + excl + v;  // END position (padded space)
  cnt[tid] = excl;
  __syncthreads();
  for (int i = istart + tid; i < iend; i += 256) {
    const unsigned int it = itemsE[i];
    int r = atomicAdd(&cnt[it >> 18], 1);
    lists_e[istart + r] = (int)(it & 0x3FFFFu);
  }
}

// ---------------- MFMA linear: y = x @ W^T + b, fp32 in, bf16-packed out ----------------
// Split-bf16 exactness: x = xh+xl, w = wh+wl (each bf16); y ~= xh*wh + xh*wl + xl*wh.
// v_mfma_f32_16x16x32_bf16 per lane l: A row = l&15, k = (l>>4)*8+e; C/D col = l&15,
// row = (l>>4)*4+j. W in registers (64 VGPR); x register-prefetched one tile ahead
// (hides HBM latency under convert+MFMA); epilogue staged through a per-wave 2 KB
// LDS region so each wave's global store is one contiguous 2 KB (2x dwordx4/lane).
__device__ void linear_mfma(unsigned char* smem,
                            const float* __restrict__ x,
                            const float* __restrict__ W,
                            const float* __restrict__ b,
                            unsigned int* __restrict__ y,
                            int ntiles, int wid, int nw) {
  const int l = threadIdx.x & 63;
  const int c = l & 15;
  const int kb = l >> 4;

  // Pre-split W fragments (registers only).
  short8v bh[4][2], bl[4][2];
  float bias[4];
#pragma unroll
  for (int cb = 0; cb < 4; ++cb) {
    bias[cb] = b[cb * 16 + c];
#pragma unroll
    for (int ks = 0; ks < 2; ++ks) {
      const float* wp = W + (size_t)(cb * 16 + c) * DDIM + ks * 32 + kb * 8;
      const float4 w0 = *reinterpret_cast<const float4*>(wp);
      const float4 w1 = *reinterpret_cast<const float4*>(wp + 4);
      const float wf[8] = {w0.x, w0.y, w0.z, w0.w, w1.x, w1.y, w1.z, w1.w};
      short8v h, lo;
#pragma unroll
      for (int e = 0; e < 8; ++e) {
        const unsigned short hb = bf_rne(wf[e]);
        h[e] = (short)hb;
        lo[e] = (short)bf_rne(wf[e] - bf_val(hb));
      }
      bh[cb][ks] = h;
      bl[cb][ks] = lo;
    }
  }

  unsigned int* st =
      (unsigned int*)(smem + ((threadIdx.x >> 6) << 11));  // per-wave 2 KB

  int t = wid;
  if (t >= ntiles) return;
  const float* xp0 = x + (size_t)(t * 16 + c) * DDIM + kb * 8;
  float4 c0 = *reinterpret_cast<const float4*>(xp0);
  float4 c1 = *reinterpret_cast<const float4*>(xp0 + 4);
  float4 c2 = *reinterpret_cast<const float4*>(xp0 + 32);
  float4 c3 = *reinterpret_cast<const float4*>(xp0 + 36);

  for (;;) {
    // Prefetch next tile's x (issued before current tile's compute chain).
    const int tn = t + nw;
    float4 n0, n1, n2, n3;
    if (tn < ntiles) {
      const float* xpn = x + (size_t)(tn * 16 + c) * DDIM + kb * 8;
      n0 = *reinterpret_cast<const float4*>(xpn);
      n1 = *reinterpret_cast<const float4*>(xpn + 4);
      n2 = *reinterpret_cast<const float4*>(xpn + 32);
      n3 = *reinterpret_cast<const float4*>(xpn + 36);
    }

    // Convert current tile to split-bf16 fragments.
    short8v ah[2], al[2];
    {
      const float xf0[8] = {c0.x, c0.y, c0.z, c0.w, c1.x, c1.y, c1.z, c1.w};
      const float xf1[8] = {c2.x, c2.y, c2.z, c2.w, c3.x, c3.y, c3.z, c3.w};
      short8v h0, l0, h1, l1;
#pragma unroll
      for (int e = 0; e < 8; ++e) {
        unsigned short hb = bf_rne(xf0[e]);
        h0[e] = (short)hb;
        l0[e] = (short)bf_rne(xf0[e] - bf_val(hb));
        hb = bf_rne(xf1[e]);
        h1[e] = (short)hb;
        l1[e] = (short)bf_rne(xf1[e] - bf_val(hb));
      }
      ah[0] = h0; al[0] = l0; ah[1] = h1; al[1] = l1;
    }

    f32x4 acc[4];
#pragma unroll
    for (int cb = 0; cb < 4; ++cb) {
      acc[cb][0] = bias[cb];
      acc[cb][1] = bias[cb];
      acc[cb][2] = bias[cb];
      acc[cb][3] = bias[cb];
    }
#pragma unroll
    for (int ks = 0; ks < 2; ++ks)
#pragma unroll
      for (int cb = 0; cb < 4; ++cb) {
        acc[cb] = __builtin_amdgcn_mfma_f32_16x16x32_bf16(ah[ks], bh[cb][ks],
                                                          acc[cb], 0, 0, 0);
        acc[cb] = __builtin_amdgcn_mfma_f32_16x16x32_bf16(ah[ks], bl[cb][ks],
                                                          acc[cb], 0, 0, 0);
        acc[cb] = __builtin_amdgcn_mfma_f32_16x16x32_bf16(al[ks], bh[cb][ks],
                                                          acc[cb], 0, 0, 0);
      }

    // Epilogue: stage the wave's 16x128B tile in LDS, read back lane-linear,
    // store one contiguous 2 KB block (2x dwordx4 per lane).
#pragma unroll
    for (int j = 0; j < 4; ++j) {
      st[(kb * 4 + j) * 32 + c] = pack_bf2(acc[0][j], acc[2][j]);
      st[(kb * 4 + j) * 32 + 16 + c] = pack_bf2(acc[1][j], acc[3][j]);
    }
    // same-wave LDS RAW: compiler inserts the lgkmcnt wait
    const uint4* stv = reinterpret_cast<const uint4*>(st);
    const uint4 o0 = stv[l * 2];
    const uint4 o1 = stv[l * 2 + 1];
    uint4* yp = reinterpret_cast<uint4*>(y + (size_t)t * 512);
    yp[l * 2] = o0;
    yp[l * 2 + 1] = o1;

    if (tn >= ntiles) break;
    t = tn;
    c0 = n0; c1 = n1; c2 = n2; c3 = n3;
  }
}

// Merged dispatch: CSR pass-B (587 blocks, ~all co-resident) + layer-1 linear.
__global__ __launch_bounds__(256, 3) void build_lin_kernel(
    const int* __restrict__ cntU, const int* __restrict__ cntE,
    const unsigned int* __restrict__ itemsU,
    const unsigned int* __restrict__ itemsE, int* __restrict__ offs,
    unsigned short* __restrict__ lists_u, int* __restrict__ lists_e,
    const float* __restrict__ xu, const float* __restrict__ Wu,
    const float* __restrict__ bu, unsigned int* __restrict__ yu,
    const float* __restrict__ xe, const float* __restrict__ We,
    const float* __restrict__ be, unsigned int* __restrict__ ye) {
  __shared__ __align__(16) unsigned char smem[8192];
  const int bx = blockIdx.x;
  if (bx < NBU) {
    build_user_body(smem, cntU, itemsU, offs, lists_u, bx);
  } else if (bx < NB) {
    build_event_body(smem, cntE, itemsE, offs, lists_e, bx - NBU);
  } else {
    const int wid = (bx - NB) * 4 + (threadIdx.x >> 6);
    const int nw = (BL_GRID - NB) * 4;
    linear_mfma(smem, xu, Wu, bu, yu, TU16, wid, nw);
    linear_mfma(smem, xe, We, be, ye, TE16, wid, nw);
  }
}

// Layer-2 linear (standalone, depends on gather-1 output).
__global__ __launch_bounds__(256, 3) void linear_kernel(
    const float* __restrict__ xu, const float* __restrict__ Wu,
    const float* __restrict__ bu, unsigned int* __restrict__ yu,
    const float* __restrict__ xe, const float* __restrict__ We,
    const float* __restrict__ be, unsigned int* __restrict__ ye) {
  __shared__ __align__(16) unsigned char smem[8192];
  const int wid = blockIdx.x * 4 + (threadIdx.x >> 6);
  const int nw = LIN2_GRID * 4;
  linear_mfma(smem, xu, Wu, bu, yu, TU16, wid, nw);
  linear_mfma(smem, xe, We, be, ye, TE16, wid, nw);
}

// ---------------- Fused gather aggregation (phase-sequential, prefetched) ----------------
// Eighth-wave (8 lanes) per node; lane dl holds table words 4dl..4dl+3 as one uint4.
// Table word w = (dim w lo, dim w+32 hi). offs are END positions in padded
// item-space; first node of each bucket starts at the bucket base (b*CAP).
__device__ __forceinline__ void seg_bounds(
    const int* __restrict__ offs, int obase, int node, int shift, int cap,
    int& s, int& e) {
  e = offs[obase + node];
  const int ib = node & ((1 << shift) - 1);
  s = (ib == 0) ? (node >> shift) * cap : offs[obase + node - 1];
}

template <typename IdxT>
__device__ __forceinline__ void gather_phase(
    const int* __restrict__ offs, const IdxT* __restrict__ lists,
    const uint4* __restrict__ lin_self, const uint4* __restrict__ lin_other,
    float4* __restrict__ out, int n, int obase, int shift, int cap,
    int stream_id, int nstreams, int dl) {
  int node = stream_id;
  if (node >= n) return;
  int start, end;
  seg_bounds(offs, obase, node, shift, cap, start, end);
  uint4 sv = lin_self[(size_t)node * 8 + dl];

  while (true) {
    // Prefetch next node's descriptors (issued before the gather chain).
    const int nnode = node + nstreams;
    int nstart = 0, nend = 0;
    uint4 nsv = make_uint4(0u, 0u, 0u, 0u);
    if (nnode < n) {
      seg_bounds(offs, obase, nnode, shift, cap, nstart, nend);
      nsv = lin_self[(size_t)nnode * 8 + dl];
    }

    float a0 = bf_lo(sv.x), a4 = bf_hi(sv.x);
    float a1 = bf_lo(sv.y), a5 = bf_hi(sv.y);
    float a2 = bf_lo(sv.z), a6 = bf_hi(sv.z);
    float a3 = bf_lo(sv.w), a7 = bf_hi(sv.w);
    int j = start;
    for (; j + 8 <= end; j += 8) {
      int o[8];
#pragma unroll
      for (int t = 0; t < 8; ++t) o[t] = (int)lists[j + t];
      uint4 v[8];
#pragma unroll
      for (int t = 0; t < 8; ++t) v[t] = lin_other[(size_t)o[t] * 8 + dl];
#pragma unroll
      for (int t = 0; t < 8; ++t) {
        a0 += bf_lo(v[t].x); a4 += bf_hi(v[t].x);
        a1 += bf_lo(v[t].y); a5 += bf_hi(v[t].y);
        a2 += bf_lo(v[t].z); a6 += bf_hi(v[t].z);
        a3 += bf_lo(v[t].w); a7 += bf_hi(v[t].w);
      }
    }
    for (; j + 4 <= end; j += 4) {
      int o[4];
#pragma unroll
      for (int t = 0; t < 4; ++t) o[t] = (int)lists[j + t];
      uint4 v[4];
#pragma unroll
      for (int t = 0; t < 4; ++t) v[t] = lin_other[(size_t)o[t] * 8 + dl];
#pragma unroll
      for (int t = 0; t < 4; ++t) {
        a0 += bf_lo(v[t].x); a4 += bf_hi(v[t].x);
        a1 += bf_lo(v[t].y); a5 += bf_hi(v[t].y);
        a2 += bf_lo(v[t].z); a6 += bf_hi(v[t].z);
        a3 += bf_lo(v[t].w); a7 += bf_hi(v[t].w);
      }
    }
    for (; j < end; ++j) {
      const int o0 = (int)lists[j];
      const uint4 v0 = lin_other[(size_t)o0 * 8 + dl];
      a0 += bf_lo(v0.x); a4 += bf_hi(v0.x);
      a1 += bf_lo(v0.y); a5 += bf_hi(v0.y);
      a2 += bf_lo(v0.z); a6 += bf_hi(v0.z);
      a3 += bf_lo(v0.w); a7 += bf_hi(v0.w);
    }
    const float inv = 1.0f / (float)(end - start + 1);
    out[(size_t)node * 16 + dl] = make_float4(a0 * inv, a1 * inv, a2 * inv, a3 * inv);
    out[(size_t)node * 16 + 8 + dl] = make_float4(a4 * inv, a5 * inv, a6 * inv, a7 * inv);

    if (nnode >= n) break;
    node = nnode;
    start = nstart;
    end = nend;
    sv = nsv;
  }
}

__global__ __launch_bounds__(256) void gather_fused_kernel(
    const int* __restrict__ offs, const unsigned short* __restrict__ lists_u,
    const int* __restrict__ lists_e, const unsigned int* __restrict__ lin_u,
    const unsigned int* __restrict__ lin_e, float* __restrict__ out_u,
    float* __restrict__ out_e) {
  const int lane = threadIdx.x & 63;
  const int dl = lane & 7;
  const int ew = ((blockIdx.x * (blockDim.x >> 6) + (threadIdx.x >> 6)) << 3) |
                 (lane >> 3);               // global eighth-wave id
  const int nstreams = GGRID * 32;          // 65536 streams, both phases
  gather_phase<unsigned short>(
      offs, lists_u, reinterpret_cast<const uint4*>(lin_u),
      reinterpret_cast<const uint4*>(lin_e), reinterpret_cast<float4*>(out_u),
      NUM_USER, 0, 9, CAPU, ew, nstreams, dl);
  gather_phase<int>(
      offs, lists_e, reinterpret_cast<const uint4*>(lin_e),
      reinterpret_cast<const uint4*>(lin_u), reinterpret_cast<float4*>(out_e),
      NUM_EVENT, NUM_USER, 8, CAPE, ew, nstreams, dl);
}

// ---------------- Launch ----------------

extern "C" void kernel_launch(void* const* d_in, const int* in_sizes, int n_in,
                              void* d_out, int out_size, void* d_ws,
                              size_t ws_size, hipStream_t stream) {
  const float* x_user = (const float*)d_in[0];
  const float* x_event = (const float*)d_in[1];
  const int* src = (const int*)d_in[2];
  const int* dst = (const int*)d_in[3];
  const float* Wu0 = (const float*)d_in[4];
  const float* bu0 = (const float*)d_in[5];
  const float* We0 = (const float*)d_in[6];
  const float* be0 = (const float*)d_in[7];
  const float* Wu1 = (const float*)d_in[8];
  const float* bu1 = (const float*)d_in[9];
  const float* We1 = (const float*)d_in[10];
  const float* be1 = (const float*)d_in[11];

  // Workspace layout (~40 MB, below the proven-safe 47 MB of R0-R2).
  unsigned int* lin_u = (unsigned int*)d_ws;            // 6.4M u32 = 25.6 MB
  unsigned int* lin_e = lin_u + (size_t)NUM_USER * 32;  // 1.6M u32 = 6.4 MB
  int* offs = (int*)(lin_e + (size_t)NUM_EVENT * 32);   // 250,000 = 1.0 MB
  int* cntU = offs + (NUM_USER + NUM_EVENT);            // 391
  int* cntE = cntU + NBU;                               // 196
  int* lists_e = (int*)(cntE + NBE);                    // NBE*CAPE int = 4.42 MB
  unsigned short* lists_u =
      (unsigned short*)(lists_e + (size_t)NBE * CAPE);  // NBU*CAPU u16 = 2.40 MB

  // items buffers overlay d_out (64 MB): consumed entirely inside
  // build_lin_kernel, which completes (stream order) before gather-1 writes out.
  unsigned int* itemsU = (unsigned int*)d_out;          // NBU*CAPU u32 = 4.80 MB
  unsigned int* itemsE = itemsU + (size_t)NBU * CAPU;   // NBE*CAPE u32 = 4.42 MB

  float* out_u = (float*)d_out;
  float* out_e = out_u + (size_t)NUM_USER * DDIM;

  // Zero bucket counters in one memset.
  hipMemsetAsync(cntU, 0, (NBU + NBE) * sizeof(int), stream);

  // --- CSR scatter (single pass, fixed-capacity buckets) ---
  bucket_scatter_kernel<<<NCH, 256, 0, stream>>>(src, dst, cntU, cntE, itemsU,
                                                 itemsE);

  // ---- CSR pass-B + Layer-1 MFMA linear (merged) ----
  build_lin_kernel<<<BL_GRID, 256, 0, stream>>>(
      cntU, cntE, itemsU, itemsE, offs, lists_u, lists_e,
      x_user, Wu0, bu0, lin_u, x_event, We0, be0, lin_e);
  gather_fused_kernel<<<GGRID, 256, 0, stream>>>(
      offs, lists_u, lists_e, lin_u, lin_e, out_u, out_e);

  // ---- Layer 2 ----
  linear_kernel<<<LIN2_GRID, 256, 0, stream>>>(
      out_u, Wu1, bu1, lin_u, out_e, We1, be1, lin_e);
  gather_fused_kernel<<<GGRID, 256, 0, stream>>>(
      offs, lists_u, lists_e, lin_u, lin_e, out_u, out_e);
}

// Round 8
// 354.960 us; speedup vs baseline: 1.0650x; 1.0650x over previous
//
#include <hip/hip_runtime.h>

#define NUM_USER 200000
#define NUM_EVENT 50000
#define NUM_EDGES 1000000
#define DDIM 64

// Bucketed CSR build: user buckets span 512 nodes, event buckets span 256.
#define NBU 391                // 391*512 = 200192 >= NUM_USER
#define NBE 196                // 196*256 = 50176 >= NUM_EVENT
#define NB (NBU + NBE)         // 587
#define CHUNK 2048
#define NCH ((NUM_EDGES + CHUNK - 1) / CHUNK)  // 489

// Fixed bucket capacities (counting-sort without count/scan passes).
// User bucket ~ Binomial(1M, 512/200000): mean 2560, sd ~50.5 -> 3072 = +10sd.
// Event bucket ~ Binomial(1M, 256/50000): mean 5120, sd ~71   -> 5632 = +7sd.
#define CAPU 3072
#define CAPE 5632

// MFMA linear: 16-row tiles per wave, prefetched, LDS-staged coalesced stores.
#define TU16 (NUM_USER / 16)   // 12500
#define TE16 (NUM_EVENT / 16)  // 3125
#define BL_GRID 2048           // 587 build blocks + 1461 linear blocks
#define LIN2_GRID 768

// Gather: persistent grid, phase-sequential
#define GGRID 2048

typedef __attribute__((ext_vector_type(8))) short short8v;  // 8 bf16 (4 VGPRs)
typedef __attribute__((ext_vector_type(4))) float f32x4;    // MFMA accumulator

// bf16 pair packing. Table word layout (MFMA-epilogue-native):
//   word w of a row (w=0..31) = (bf16(dim w+32) << 16) | bf16(dim w)
__device__ __forceinline__ unsigned int pack_bf2(float lo, float hi) {
  unsigned int ul = __float_as_uint(lo);
  unsigned int uh = __float_as_uint(hi);
  ul = (ul + 0x7FFFu + ((ul >> 16) & 1u)) >> 16;
  uh = (uh + 0x7FFFu + ((uh >> 16) & 1u)) & 0xFFFF0000u;
  return uh | ul;
}
__device__ __forceinline__ float bf_lo(unsigned int v) { return __uint_as_float(v << 16); }
__device__ __forceinline__ float bf_hi(unsigned int v) { return __uint_as_float(v & 0xFFFF0000u); }
__device__ __forceinline__ unsigned short bf_rne(float f) {
  unsigned int u = __float_as_uint(f);
  return (unsigned short)((u + 0x7FFFu + ((u >> 16) & 1u)) >> 16);
}
__device__ __forceinline__ float bf_val(unsigned short h) {
  return __uint_as_float(((unsigned int)h) << 16);
}

// ---------------- Scatter: single pass, fixed-capacity buckets ----------------
// itemU = (dst&511)<<16 | src ; itemE = (src&255)<<18 | dst
__global__ __launch_bounds__(256) void bucket_scatter_kernel(
    const int* __restrict__ src, const int* __restrict__ dst,
    int* __restrict__ cntU, int* __restrict__ cntE,
    unsigned int* __restrict__ itemsU, unsigned int* __restrict__ itemsE) {
  __shared__ int cnt[NB];
  __shared__ int cur[NB];
  for (int i = threadIdx.x; i < NB; i += 256) cnt[i] = 0;
  __syncthreads();
  const int e0 = blockIdx.x * CHUNK;
  const int e1 = min(e0 + CHUNK, NUM_EDGES);
  for (int i = e0 + threadIdx.x; i < e1; i += 256) {
    atomicAdd(&cnt[dst[i] >> 9], 1);
    atomicAdd(&cnt[NBU + (src[i] >> 8)], 1);
  }
  __syncthreads();
  for (int i = threadIdx.x; i < NB; i += 256) {
    int c = cnt[i];
    if (c) {
      if (i < NBU)
        cur[i] = i * CAPU + atomicAdd(&cntU[i], c);
      else
        cur[i] = (i - NBU) * CAPE + atomicAdd(&cntE[i - NBU], c);
    } else {
      cur[i] = 0;
    }
  }
  __syncthreads();
  for (int i = e0 + threadIdx.x; i < e1; i += 256) {
    const int s = src[i];
    const int d = dst[i];
    int r = atomicAdd(&cur[d >> 9], 1);
    itemsU[r] = ((unsigned int)(d & 511) << 16) | (unsigned int)s;
    int r2 = atomicAdd(&cur[NBU + (s >> 8)], 1);
    itemsE[r2] = ((unsigned int)(s & 255) << 18) | (unsigned int)d;
  }
}

// ---------------- Pass B bodies (share a union'd LDS buffer, 8192 B) ----------------

// user: one block per bucket of 512 users. smem: 512+256 ints = 3072 B.
__device__ __forceinline__ void build_user_body(
    unsigned char* smem, const int* __restrict__ cntU,
    const unsigned int* __restrict__ itemsU, int* __restrict__ offs,
    unsigned short* __restrict__ lists_u, int b) {
  int* cnt = (int*)smem;       // 512
  int* part = cnt + 512;       // 256
  const int istart = b * CAPU;
  const int iend = istart + cntU[b];
  const int tid = threadIdx.x;
  for (int i = tid; i < 512; i += 256) cnt[i] = 0;
  __syncthreads();
  for (int i = istart + tid; i < iend; i += 256)
    atomicAdd(&cnt[itemsU[i] >> 16], 1);
  __syncthreads();
  const int v0 = cnt[tid * 2];
  const int v1 = cnt[tid * 2 + 1];
  part[tid] = v0 + v1;
  __syncthreads();
  for (int off = 1; off < 256; off <<= 1) {
    int t = (tid >= off) ? part[tid - off] : 0;
    __syncthreads();
    part[tid] += t;
    __syncthreads();
  }
  int run = (tid == 0) ? 0 : part[tid - 1];
  const int node0 = b * 512;
  const int n = node0 + tid * 2;
  if (n < NUM_USER) offs[n] = istart + run + v0;  // END position (padded space)
  cnt[tid * 2] = run;                             // exclusive -> cursor
  run += v0;
  if (n + 1 < NUM_USER) offs[n + 1] = istart + run + v1;
  cnt[tid * 2 + 1] = run;
  __syncthreads();
  for (int i = istart + tid; i < iend; i += 256) {
    const unsigned int it = itemsU[i];
    int r = atomicAdd(&cnt[it >> 16], 1);
    lists_u[istart + r] = (unsigned short)(it & 0xFFFFu);
  }
}

// event: one block per bucket of 256 events. smem: 512 ints = 2048 B.
__device__ __forceinline__ void build_event_body(
    unsigned char* smem, const int* __restrict__ cntE,
    const unsigned int* __restrict__ itemsE, int* __restrict__ offs,
    int* __restrict__ lists_e, int b) {
  int* cnt = (int*)smem;   // 256
  int* s2 = cnt + 256;     // 256
  const int istart = b * CAPE;
  const int iend = istart + cntE[b];
  const int tid = threadIdx.x;
  cnt[tid] = 0;
  __syncthreads();
  for (int i = istart + tid; i < iend; i += 256)
    atomicAdd(&cnt[itemsE[i] >> 18], 1);
  __syncthreads();
  const int v = cnt[tid];
  s2[tid] = v;
  __syncthreads();
  for (int off = 1; off < 256; off <<= 1) {
    int t = (tid >= off) ? s2[tid - off] : 0;
    __syncthreads();
    s2[tid] += t;
    __syncthreads();
  }
  const int excl = s2[tid] - v;
  const int e0 = b * 256;
  if (e0 + tid < NUM_EVENT)
    offs[NUM_USER + e0 + tid] = istart + excl + v;  // END position (padded space)
  cnt[tid] = excl;
  __syncthreads();
  for (int i = istart + tid; i < iend; i += 256) {
    const unsigned int it = itemsE[i];
    int r = atomicAdd(&cnt[it >> 18], 1);
    lists_e[istart + r] = (int)(it & 0x3FFFFu);
  }
}

// ---------------- MFMA linear: y = x @ W^T + b, fp32 in, bf16-packed out ----------------
// Split-bf16 exactness: x = xh+xl, w = wh+wl (each bf16); y ~= xh*wh + xh*wl + xl*wh.
// W lives in registers (64 VGPR of fragments) — NO __launch_bounds__ min-waves here:
// R7's (256,3) capped VGPR at 84 and spilled the W frags to scratch (~250 MB of
// scratch traffic, WRITE_SIZE 232 MB). Let the allocator use ~150 VGPR.
// x register-prefetched one tile ahead; epilogue staged through per-wave 2 KB LDS,
// read back and stored lane-contiguous (2x 1024 B bursts).
__device__ void linear_mfma(unsigned char* smem,
                            const float* __restrict__ x,
                            const float* __restrict__ W,
                            const float* __restrict__ b,
                            unsigned int* __restrict__ y,
                            int ntiles, int wid, int nw) {
  const int l = threadIdx.x & 63;
  const int c = l & 15;
  const int kb = l >> 4;

  // Pre-split W fragments (registers only).
  short8v bh[4][2], bl[4][2];
  float bias[4];
#pragma unroll
  for (int cb = 0; cb < 4; ++cb) {
    bias[cb] = b[cb * 16 + c];
#pragma unroll
    for (int ks = 0; ks < 2; ++ks) {
      const float* wp = W + (size_t)(cb * 16 + c) * DDIM + ks * 32 + kb * 8;
      const float4 w0 = *reinterpret_cast<const float4*>(wp);
      const float4 w1 = *reinterpret_cast<const float4*>(wp + 4);
      const float wf[8] = {w0.x, w0.y, w0.z, w0.w, w1.x, w1.y, w1.z, w1.w};
      short8v h, lo;
#pragma unroll
      for (int e = 0; e < 8; ++e) {
        const unsigned short hb = bf_rne(wf[e]);
        h[e] = (short)hb;
        lo[e] = (short)bf_rne(wf[e] - bf_val(hb));
      }
      bh[cb][ks] = h;
      bl[cb][ks] = lo;
    }
  }

  unsigned int* st =
      (unsigned int*)(smem + ((threadIdx.x >> 6) << 11));  // per-wave 2 KB

  int t = wid;
  if (t >= ntiles) return;
  const float* xp0 = x + (size_t)(t * 16 + c) * DDIM + kb * 8;
  float4 c0 = *reinterpret_cast<const float4*>(xp0);
  float4 c1 = *reinterpret_cast<const float4*>(xp0 + 4);
  float4 c2 = *reinterpret_cast<const float4*>(xp0 + 32);
  float4 c3 = *reinterpret_cast<const float4*>(xp0 + 36);

  for (;;) {
    // Prefetch next tile's x (issued before current tile's compute chain).
    const int tn = t + nw;
    float4 n0, n1, n2, n3;
    if (tn < ntiles) {
      const float* xpn = x + (size_t)(tn * 16 + c) * DDIM + kb * 8;
      n0 = *reinterpret_cast<const float4*>(xpn);
      n1 = *reinterpret_cast<const float4*>(xpn + 4);
      n2 = *reinterpret_cast<const float4*>(xpn + 32);
      n3 = *reinterpret_cast<const float4*>(xpn + 36);
    }

    // Convert current tile to split-bf16 fragments.
    short8v ah[2], al[2];
    {
      const float xf0[8] = {c0.x, c0.y, c0.z, c0.w, c1.x, c1.y, c1.z, c1.w};
      const float xf1[8] = {c2.x, c2.y, c2.z, c2.w, c3.x, c3.y, c3.z, c3.w};
      short8v h0, l0, h1, l1;
#pragma unroll
      for (int e = 0; e < 8; ++e) {
        unsigned short hb = bf_rne(xf0[e]);
        h0[e] = (short)hb;
        l0[e] = (short)bf_rne(xf0[e] - bf_val(hb));
        hb = bf_rne(xf1[e]);
        h1[e] = (short)hb;
        l1[e] = (short)bf_rne(xf1[e] - bf_val(hb));
      }
      ah[0] = h0; al[0] = l0; ah[1] = h1; al[1] = l1;
    }

    f32x4 acc[4];
#pragma unroll
    for (int cb = 0; cb < 4; ++cb) {
      acc[cb][0] = bias[cb];
      acc[cb][1] = bias[cb];
      acc[cb][2] = bias[cb];
      acc[cb][3] = bias[cb];
    }
#pragma unroll
    for (int ks = 0; ks < 2; ++ks)
#pragma unroll
      for (int cb = 0; cb < 4; ++cb) {
        acc[cb] = __builtin_amdgcn_mfma_f32_16x16x32_bf16(ah[ks], bh[cb][ks],
                                                          acc[cb], 0, 0, 0);
        acc[cb] = __builtin_amdgcn_mfma_f32_16x16x32_bf16(ah[ks], bl[cb][ks],
                                                          acc[cb], 0, 0, 0);
        acc[cb] = __builtin_amdgcn_mfma_f32_16x16x32_bf16(al[ks], bh[cb][ks],
                                                          acc[cb], 0, 0, 0);
      }

    // Epilogue: stage the wave's 16x128B tile in LDS, read back lane-contiguous,
    // store two 1024 B contiguous bursts.
#pragma unroll
    for (int j = 0; j < 4; ++j) {
      st[(kb * 4 + j) * 32 + c] = pack_bf2(acc[0][j], acc[2][j]);
      st[(kb * 4 + j) * 32 + 16 + c] = pack_bf2(acc[1][j], acc[3][j]);
    }
    // same-wave LDS RAW: compiler inserts the lgkmcnt wait
    const uint4* stv = reinterpret_cast<const uint4*>(st);
    const uint4 o0 = stv[l];
    const uint4 o1 = stv[64 + l];
    uint4* yp = reinterpret_cast<uint4*>(y + (size_t)t * 512);
    yp[l] = o0;
    yp[64 + l] = o1;

    if (tn >= ntiles) break;
    t = tn;
    c0 = n0; c1 = n1; c2 = n2; c3 = n3;
  }
}

// Merged dispatch: CSR pass-B (587 blocks, ~all co-resident) + layer-1 linear.
__global__ __launch_bounds__(256) void build_lin_kernel(
    const int* __restrict__ cntU, const int* __restrict__ cntE,
    const unsigned int* __restrict__ itemsU,
    const unsigned int* __restrict__ itemsE, int* __restrict__ offs,
    unsigned short* __restrict__ lists_u, int* __restrict__ lists_e,
    const float* __restrict__ xu, const float* __restrict__ Wu,
    const float* __restrict__ bu, unsigned int* __restrict__ yu,
    const float* __restrict__ xe, const float* __restrict__ We,
    const float* __restrict__ be, unsigned int* __restrict__ ye) {
  __shared__ __align__(16) unsigned char smem[8192];
  const int bx = blockIdx.x;
  if (bx < NBU) {
    build_user_body(smem, cntU, itemsU, offs, lists_u, bx);
  } else if (bx < NB) {
    build_event_body(smem, cntE, itemsE, offs, lists_e, bx - NBU);
  } else {
    const int wid = (bx - NB) * 4 + (threadIdx.x >> 6);
    const int nw = (BL_GRID - NB) * 4;
    linear_mfma(smem, xu, Wu, bu, yu, TU16, wid, nw);
    linear_mfma(smem, xe, We, be, ye, TE16, wid, nw);
  }
}

// Layer-2 linear (standalone, depends on gather-1 output).
__global__ __launch_bounds__(256) void linear_kernel(
    const float* __restrict__ xu, const float* __restrict__ Wu,
    const float* __restrict__ bu, unsigned int* __restrict__ yu,
    const float* __restrict__ xe, const float* __restrict__ We,
    const float* __restrict__ be, unsigned int* __restrict__ ye) {
  __shared__ __align__(16) unsigned char smem[8192];
  const int wid = blockIdx.x * 4 + (threadIdx.x >> 6);
  const int nw = LIN2_GRID * 4;
  linear_mfma(smem, xu, Wu, bu, yu, TU16, wid, nw);
  linear_mfma(smem, xe, We, be, ye, TE16, wid, nw);
}

// ---------------- Fused gather aggregation (phase-sequential, prefetched) ----------------
// Eighth-wave (8 lanes) per node; lane dl holds table words 4dl..4dl+3 as one uint4.
// Table word w = (dim w lo, dim w+32 hi). offs are END positions in padded
// item-space; first node of each bucket starts at the bucket base (b*CAP).
__device__ __forceinline__ void seg_bounds(
    const int* __restrict__ offs, int obase, int node, int shift, int cap,
    int& s, int& e) {
  e = offs[obase + node];
  const int ib = node & ((1 << shift) - 1);
  s = (ib == 0) ? (node >> shift) * cap : offs[obase + node - 1];
}

template <typename IdxT>
__device__ __forceinline__ void gather_phase(
    const int* __restrict__ offs, const IdxT* __restrict__ lists,
    const uint4* __restrict__ lin_self, const uint4* __restrict__ lin_other,
    float4* __restrict__ out, int n, int obase, int shift, int cap,
    int stream_id, int nstreams, int dl) {
  int node = stream_id;
  if (node >= n) return;
  int start, end;
  seg_bounds(offs, obase, node, shift, cap, start, end);
  uint4 sv = lin_self[(size_t)node * 8 + dl];

  while (true) {
    // Prefetch next node's descriptors (issued before the gather chain).
    const int nnode = node + nstreams;
    int nstart = 0, nend = 0;
    uint4 nsv = make_uint4(0u, 0u, 0u, 0u);
    if (nnode < n) {
      seg_bounds(offs, obase, nnode, shift, cap, nstart, nend);
      nsv = lin_self[(size_t)nnode * 8 + dl];
    }

    float a0 = bf_lo(sv.x), a4 = bf_hi(sv.x);
    float a1 = bf_lo(sv.y), a5 = bf_hi(sv.y);
    float a2 = bf_lo(sv.z), a6 = bf_hi(sv.z);
    float a3 = bf_lo(sv.w), a7 = bf_hi(sv.w);
    int j = start;
    for (; j + 8 <= end; j += 8) {
      int o[8];
#pragma unroll
      for (int t = 0; t < 8; ++t) o[t] = (int)lists[j + t];
      uint4 v[8];
#pragma unroll
      for (int t = 0; t < 8; ++t) v[t] = lin_other[(size_t)o[t] * 8 + dl];
#pragma unroll
      for (int t = 0; t < 8; ++t) {
        a0 += bf_lo(v[t].x); a4 += bf_hi(v[t].x);
        a1 += bf_lo(v[t].y); a5 += bf_hi(v[t].y);
        a2 += bf_lo(v[t].z); a6 += bf_hi(v[t].z);
        a3 += bf_lo(v[t].w); a7 += bf_hi(v[t].w);
      }
    }
    for (; j + 4 <= end; j += 4) {
      int o[4];
#pragma unroll
      for (int t = 0; t < 4; ++t) o[t] = (int)lists[j + t];
      uint4 v[4];
#pragma unroll
      for (int t = 0; t < 4; ++t) v[t] = lin_other[(size_t)o[t] * 8 + dl];
#pragma unroll
      for (int t = 0; t < 4; ++t) {
        a0 += bf_lo(v[t].x); a4 += bf_hi(v[t].x);
        a1 += bf_lo(v[t].y); a5 += bf_hi(v[t].y);
        a2 += bf_lo(v[t].z); a6 += bf_hi(v[t].z);
        a3 += bf_lo(v[t].w); a7 += bf_hi(v[t].w);
      }
    }
    for (; j < end; ++j) {
      const int o0 = (int)lists[j];
      const uint4 v0 = lin_other[(size_t)o0 * 8 + dl];
      a0 += bf_lo(v0.x); a4 += bf_hi(v0.x);
      a1 += bf_lo(v0.y); a5 += bf_hi(v0.y);
      a2 += bf_lo(v0.z); a6 += bf_hi(v0.z);
      a3 += bf_lo(v0.w); a7 += bf_hi(v0.w);
    }
    const float inv = 1.0f / (float)(end - start + 1);
    out[(size_t)node * 16 + dl] = make_float4(a0 * inv, a1 * inv, a2 * inv, a3 * inv);
    out[(size_t)node * 16 + 8 + dl] = make_float4(a4 * inv, a5 * inv, a6 * inv, a7 * inv);

    if (nnode >= n) break;
    node = nnode;
    start = nstart;
    end = nend;
    sv = nsv;
  }
}

__global__ __launch_bounds__(256) void gather_fused_kernel(
    const int* __restrict__ offs, const unsigned short* __restrict__ lists_u,
    const int* __restrict__ lists_e, const unsigned int* __restrict__ lin_u,
    const unsigned int* __restrict__ lin_e, float* __restrict__ out_u,
    float* __restrict__ out_e) {
  const int lane = threadIdx.x & 63;
  const int dl = lane & 7;
  const int ew = ((blockIdx.x * (blockDim.x >> 6) + (threadIdx.x >> 6)) << 3) |
                 (lane >> 3);               // global eighth-wave id
  const int nstreams = GGRID * 32;          // 65536 streams, both phases
  gather_phase<unsigned short>(
      offs, lists_u, reinterpret_cast<const uint4*>(lin_u),
      reinterpret_cast<const uint4*>(lin_e), reinterpret_cast<float4*>(out_u),
      NUM_USER, 0, 9, CAPU, ew, nstreams, dl);
  gather_phase<int>(
      offs, lists_e, reinterpret_cast<const uint4*>(lin_e),
      reinterpret_cast<const uint4*>(lin_u), reinterpret_cast<float4*>(out_e),
      NUM_EVENT, NUM_USER, 8, CAPE, ew, nstreams, dl);
}

// ---------------- Launch ----------------

extern "C" void kernel_launch(void* const* d_in, const int* in_sizes, int n_in,
                              void* d_out, int out_size, void* d_ws,
                              size_t ws_size, hipStream_t stream) {
  const float* x_user = (const float*)d_in[0];
  const float* x_event = (const float*)d_in[1];
  const int* src = (const int*)d_in[2];
  const int* dst = (const int*)d_in[3];
  const float* Wu0 = (const float*)d_in[4];
  const float* bu0 = (const float*)d_in[5];
  const float* We0 = (const float*)d_in[6];
  const float* be0 = (const float*)d_in[7];
  const float* Wu1 = (const float*)d_in[8];
  const float* bu1 = (const float*)d_in[9];
  const float* We1 = (const float*)d_in[10];
  const float* be1 = (const float*)d_in[11];

  // Workspace layout (~40 MB, below the proven-safe 47 MB of R0-R2).
  unsigned int* lin_u = (unsigned int*)d_ws;            // 6.4M u32 = 25.6 MB
  unsigned int* lin_e = lin_u + (size_t)NUM_USER * 32;  // 1.6M u32 = 6.4 MB
  int* offs = (int*)(lin_e + (size_t)NUM_EVENT * 32);   // 250,000 = 1.0 MB
  int* cntU = offs + (NUM_USER + NUM_EVENT);            // 391
  int* cntE = cntU + NBU;                               // 196
  int* lists_e = (int*)(cntE + NBE);                    // NBE*CAPE int = 4.42 MB
  unsigned short* lists_u =
      (unsigned short*)(lists_e + (size_t)NBE * CAPE);  // NBU*CAPU u16 = 2.40 MB

  // items buffers overlay d_out (64 MB): consumed entirely inside
  // build_lin_kernel, which completes (stream order) before gather-1 writes out.
  unsigned int* itemsU = (unsigned int*)d_out;          // NBU*CAPU u32 = 4.80 MB
  unsigned int* itemsE = itemsU + (size_t)NBU * CAPU;   // NBE*CAPE u32 = 4.42 MB

  float* out_u = (float*)d_out;
  float* out_e = out_u + (size_t)NUM_USER * DDIM;

  // Zero bucket counters in one memset.
  hipMemsetAsync(cntU, 0, (NBU + NBE) * sizeof(int), stream);

  // --- CSR scatter (single pass, fixed-capacity buckets) ---
  bucket_scatter_kernel<<<NCH, 256, 0, stream>>>(src, dst, cntU, cntE, itemsU,
                                                 itemsE);

  // ---- CSR pass-B + Layer-1 MFMA linear (merged) ----
  build_lin_kernel<<<BL_GRID, 256, 0, stream>>>(
      cntU, cntE, itemsU, itemsE, offs, lists_u, lists_e,
      x_user, Wu0, bu0, lin_u, x_event, We0, be0, lin_e);
  gather_fused_kernel<<<GGRID, 256, 0, stream>>>(
      offs, lists_u, lists_e, lin_u, lin_e, out_u, out_e);

  // ---- Layer 2 ----
  linear_kernel<<<LIN2_GRID, 256, 0, stream>>>(
      out_u, Wu1, bu1, lin_u, out_e, We1, be1, lin_e);
  gather_fused_kernel<<<GGRID, 256, 0, stream>>>(
      offs, lists_u, lists_e, lin_u, lin_e, out_u, out_e);
}